// Round 3
// baseline (335.061 us; speedup 1.0000x reference)
//
#include <hip/hip_runtime.h>

// B=8, H=W=256, I_DIM=64, K_DIM=64 (hd_k=32), V_DIM=32 (hd_v=16), O_DIM=64
// NH=2, unfold: p=7, stride=21, dilation=4, npw=12 -> S=144 patches
#define BB 8
#define HH 256
#define CIN 64
#define NPW 12
#define SPP 144
#define PP 49
#define PDIM 7
#define STRIDE 21
#define DIL 4
#define NS 84

typedef __attribute__((ext_vector_type(8))) short bf16x8;
typedef __attribute__((ext_vector_type(4))) float f32x4;

#define MFMA(a, b, c) __builtin_amdgcn_mfma_f32_16x16x32_bf16((a), (b), (c), 0, 0, 0)

static __device__ __forceinline__ unsigned short f2bf(float f) {
  union { float f; unsigned u; } v; v.f = f;
  unsigned r = (v.u + 0x7fffu + ((v.u >> 16) & 1u)) >> 16;
  return (unsigned short)r;
}
static __device__ __forceinline__ float bf2f(unsigned short h) {
  union { unsigned u; float f; } v; v.u = ((unsigned)h) << 16;
  return v.f;
}
static __device__ __forceinline__ unsigned pk2(float a, float b) {
  return (unsigned)f2bf(a) | ((unsigned)f2bf(b) << 16);
}
// XOR-swizzle: 16B granules (8 shorts) within a 64-short row, granule ^ (row&7)
static __device__ __forceinline__ int swz(int col, int row) {
  return ((((col >> 3) ^ (row & 7)) & 7) << 3) | (col & 7);
}

// ---------------------------------------------------------------------------
// Kernel 1: one block per (b, patch), 4 waves, all matmul phases on MFMA.
// MFMA 16x16x32 bf16: A lane&15=m, k=(lane>>4)*8+j; B lane&15=n, same k;
// D col=lane&15, row=(lane>>4)*4+reg.
// LDS layout (short lds[20480] = 40960 B -> 4 blocks/CU):
//  [0..8191]      ph0-1: XT[src][t][c']   ph2+: KK[n][x][y']   (swizzled)
//  [8192..12287]  ph1-2: KT1[t][r0..63]   ph5+: OT[t][l']      (swizzled)
//  [12288..16383] ph1-2: KT2[t][r64..127] ph3+: stats f32[4][2][64]
//  [16384..20479] sV[rv][t']  rows 0-31 V1, 32-63 V2          (swizzled)
// ---------------------------------------------------------------------------
__global__ __launch_bounds__(256, 4) void k1_fused(
    const float* __restrict__ x1, const float* __restrict__ x2,
    const float* __restrict__ Wk, const float* __restrict__ bk,
    const float* __restrict__ Wv, const float* __restrict__ bv,
    const float* __restrict__ Wp, float* __restrict__ P)
{
  __shared__ __align__(16) short lds[20480];

  const int tid = threadIdx.x;
  const int lane = tid & 63;
  const int wid = tid >> 6;
  const int l16 = lane & 15;
  const int l4 = lane >> 4;
  const int blk = blockIdx.x;
  const int b  = blk / SPP;
  const int sp = blk % SPP;
  const int pi = sp / NPW, pj = sp % NPW;
  const int h0 = pi * STRIDE, w0 = pj * STRIDE;

  // ---- phase 0: gather x tiles into XT (bf16, transposed, swizzled) ----
  // thread = (src, half, c): c = lane, (src,half) uniform per wave.
  {
    const int c = tid & 63;
    const int g = tid >> 6;          // 0..3
    const int src = g >> 1;
    const int half = g & 1;
    const int t0 = half * 24;        // halves overlap at t=24 (same value twice)
    const float* xp = src ? x2 : x1;
    int pw = half ? 3 : 0;
    const int ph = half ? 3 : 0;
    const float* p = xp + (((size_t)(b * CIN + c)) * HH + (h0 + ph * DIL)) * HH
                     + (w0 + pw * DIL);
    float vals[25];
    #pragma unroll
    for (int q = 0; q < 25; ++q) {
      vals[q] = *p;
      ++pw; p += DIL;
      if (pw == PDIM) { pw = 0; p += DIL * HH - PDIM * DIL; }
    }
    #pragma unroll
    for (int q = 0; q < 25; ++q) {
      const int t = t0 + q;
      lds[(src * 64 + t) * 64 + swz(c, t)] = (short)f2bf(vals[q]);
    }
    // zero XT pad rows t=49..63 (shorts [3136,4096) and [7232,8192))
    unsigned* z = (unsigned*)lds;
    for (int i = tid; i < 480; i += 256) { z[1568 + i] = 0u; z[3616 + i] = 0u; }
  }
  __syncthreads();

  // ---- phase 1: projections KV[192][64px] = W(hi+lo) @ XT, MFMA ----
  // Mtiles: 0-3 K1(x1), 4-7 K2(x2), 8-9 V1(x1), 10-11 V2(x2). Wave w: 3w..3w+2.
  {
    #pragma unroll
    for (int mi = 0; mi < 3; mi++) {
      const int m = wid * 3 + mi;
      const int r0 = m * 16;
      const int src = (m < 4) ? 0 : (m < 8 ? 1 : (m < 10 ? 0 : 1));
      const int rl = r0 + l16;
      const float* wrow = (r0 < 128) ? (Wk + (size_t)rl * 64)
                                     : (Wv + (size_t)(rl - 128) * 64);
      bf16x8 ahi[2], alo[2];
      #pragma unroll
      for (int kt = 0; kt < 2; kt++) {
        const float* wp8 = wrow + kt * 32 + l4 * 8;
        float4 wa = *(const float4*)wp8;
        float4 wb = *(const float4*)(wp8 + 4);
        float wf[8] = {wa.x, wa.y, wa.z, wa.w, wb.x, wb.y, wb.z, wb.w};
        #pragma unroll
        for (int j = 0; j < 8; j++) {
          unsigned short h = f2bf(wf[j]);
          ahi[kt][j] = (short)h;
          alo[kt][j] = (short)f2bf(wf[j] - bf2f(h));
        }
      }
      float bias[4];
      #pragma unroll
      for (int i = 0; i < 4; i++) {
        int rd = r0 + l4 * 4 + i;
        bias[i] = (r0 < 128) ? bk[rd] : bv[rd - 128];
      }
      #pragma unroll
      for (int nt = 0; nt < 4; nt++) {
        const int t = nt * 16 + l16;
        f32x4 acc = {0.f, 0.f, 0.f, 0.f};
        #pragma unroll
        for (int kt = 0; kt < 2; kt++) {
          bf16x8 xb = *(const bf16x8*)
              &lds[(src * 64 + t) * 64 + ((((kt << 2) + l4) ^ (t & 7)) << 3)];
          acc = MFMA(alo[kt], xb, acc);
          acc = MFMA(ahi[kt], xb, acc);
        }
        if (r0 < 128) {
          // K row rcol -> KT1 (rcol<64) or KT2; 4 bf16 at swizzled 8B slot
          const int rcol = r0 + l4 * 4;
          const int base = (rcol < 64) ? 8192 : 12288;
          const int col = rcol & 63;
          unsigned* p = (unsigned*)&lds[base + t * 64 + swz(col, t)];
          p[0] = pk2(acc[0] + bias[0], acc[1] + bias[1]);
          p[1] = pk2(acc[2] + bias[2], acc[3] + bias[3]);
        } else {
          #pragma unroll
          for (int i = 0; i < 4; i++) {
            int rv = r0 - 128 + l4 * 4 + i;
            lds[16384 + rv * 64 + swz(t, rv)] = (short)f2bf(acc[i] + bias[i]);
          }
        }
      }
    }
  }
  __syncthreads();   // XT dead; region A becomes KK

  const float scale = 0.17677669529663687f;  // 1/sqrt(32)

  // ---- phase 2: logits KK[n][x][y] = scale * K1^T K2, one MFMA per tile ----
  // wave w: head n = w>>1, x-tiles {(w&1)*2, (w&1)*2+1}, all 4 y-tiles
  {
    const int n = wid >> 1;
    #pragma unroll
    for (int xi = 0; xi < 2; xi++) {
      const int x0 = ((wid & 1) * 2 + xi) * 16;
      const int tA = x0 + l16;
      bf16x8 a = *(const bf16x8*)
          &lds[8192 + tA * 64 + ((((n << 2) + l4) ^ (tA & 7)) << 3)];
      #pragma unroll
      for (int yt = 0; yt < 4; yt++) {
        const int y = yt * 16 + l16;
        bf16x8 bb = *(const bf16x8*)
            &lds[12288 + y * 64 + ((((n << 2) + l4) ^ (y & 7)) << 3)];
        f32x4 acc = {0.f, 0.f, 0.f, 0.f};
        acc = MFMA(a, bb, acc);
        #pragma unroll
        for (int i = 0; i < 4; i++) {
          int x = x0 + l4 * 4 + i;
          lds[(n * 64 + x) * 64 + swz(y, x)] = (short)f2bf(acc[i] * scale);
        }
      }
    }
  }
  __syncthreads();

  // ---- phase 3: softmax stats (col over x for each y; row over y for each x)
  // stats live in region B2 (KT2 dead after phase 2)
  {
    float* sStat = (float*)&lds[12288];  // [4][2][64]
    if (tid < 196) {
      int n = tid / 98;
      int r = tid % 98;
      int isRow = r >= 49;
      int j = r - (isRow ? 49 : 0);
      float mx = -1e30f;
      for (int k = 0; k < 49; k++) {
        int xr = isRow ? j : k, yc = isRow ? k : j;
        float v = bf2f((unsigned short)lds[(n * 64 + xr) * 64 + swz(yc, xr)]);
        mx = fmaxf(mx, v);
      }
      float sm = 0.f;
      for (int k = 0; k < 49; k++) {
        int xr = isRow ? j : k, yc = isRow ? k : j;
        float v = bf2f((unsigned short)lds[(n * 64 + xr) * 64 + swz(yc, xr)]);
        sm += __expf(v - mx);
      }
      int kind = isRow ? 2 : 0;
      sStat[(kind * 2 + n) * 64 + j] = mx;
      sStat[((kind + 1) * 2 + n) * 64 + j] = 1.0f / sm;
    }
  }
  __syncthreads();   // KT1 dead; region B1 becomes OT

  // ---- phase 5: AV via MFMA, exp built in-register into B-fragments ----
  // wave w: head n = w>>1, side = w&1.
  // side0: O[n*16+d][t] = (1/csum[t]) * sum_x exp(kk[x][t]-cmax[t]) * V1[d][x]
  // side1: O[32+n*16+d][x] = (1/rsum[x]) * sum_y exp(kk[x][y]-rmax[x]) * V2[d][y]
  {
    const float* sStat = (const float*)&lds[12288];
    const int n = wid >> 1;
    const int side = wid & 1;
    const int rv = side * 32 + n * 16 + l16;
    bf16x8 av[2];
    #pragma unroll
    for (int kt = 0; kt < 2; kt++)
      av[kt] = *(const bf16x8*)
          &lds[16384 + rv * 64 + ((((kt << 2) + l4) ^ (rv & 7)) << 3)];
    if (side == 0) {
      #pragma unroll
      for (int tt = 0; tt < 4; tt++) {
        const int t = tt * 16 + l16;
        const float cm = sStat[(0 * 2 + n) * 64 + t];
        const float cs = sStat[(1 * 2 + n) * 64 + t];
        f32x4 acc = {0.f, 0.f, 0.f, 0.f};
        #pragma unroll
        for (int kt = 0; kt < 2; kt++) {
          bf16x8 bfrag;
          #pragma unroll
          for (int j = 0; j < 8; j++) {
            const int x = kt * 32 + l4 * 8 + j;
            float v = bf2f((unsigned short)lds[(n * 64 + x) * 64 + swz(t, x)]);
            float e = (x < PP) ? __expf(v - cm) : 0.f;
            bfrag[j] = (short)f2bf(e);
          }
          acc = MFMA(av[kt], bfrag, acc);
        }
        const int col = n * 16 + l4 * 4;
        unsigned* p = (unsigned*)&lds[8192 + t * 64 + swz(col, t)];
        p[0] = pk2(acc[0] * cs, acc[1] * cs);
        p[1] = pk2(acc[2] * cs, acc[3] * cs);
      }
    } else {
      #pragma unroll
      for (int xt = 0; xt < 4; xt++) {
        const int x = xt * 16 + l16;
        const float rm = sStat[(2 * 2 + n) * 64 + x];
        const float rs = sStat[(3 * 2 + n) * 64 + x];
        f32x4 acc = {0.f, 0.f, 0.f, 0.f};
        #pragma unroll
        for (int kt = 0; kt < 2; kt++) {
          bf16x8 braw = *(const bf16x8*)
              &lds[(n * 64 + x) * 64 + ((((kt << 2) + l4) ^ (x & 7)) << 3)];
          bf16x8 bfrag;
          #pragma unroll
          for (int j = 0; j < 8; j++) {
            const int y = kt * 32 + l4 * 8 + j;
            float v = bf2f((unsigned short)braw[j]);
            float e = (y < PP) ? __expf(v - rm) : 0.f;
            bfrag[j] = (short)f2bf(e);
          }
          acc = MFMA(av[kt], bfrag, acc);
        }
        const int col = 32 + n * 16 + l4 * 4;
        unsigned* p = (unsigned*)&lds[8192 + x * 64 + swz(col, x)];
        p[0] = pk2(acc[0] * rs, acc[1] * rs);
        p[1] = pk2(acc[2] * rs, acc[3] * rs);
      }
    }
  }
  __syncthreads();

  // ---- phase 6: out-proj P[oc][t] = Wp(hi+lo) @ OT, wave w owns oc-tile w ----
  {
    const float* wrow = Wp + (size_t)(wid * 16 + l16) * 64;
    bf16x8 whi[2], wlo[2];
    #pragma unroll
    for (int kt = 0; kt < 2; kt++) {
      const float* wp8 = wrow + kt * 32 + l4 * 8;
      float4 wa = *(const float4*)wp8;
      float4 wb = *(const float4*)(wp8 + 4);
      float wf[8] = {wa.x, wa.y, wa.z, wa.w, wb.x, wb.y, wb.z, wb.w};
      #pragma unroll
      for (int j = 0; j < 8; j++) {
        unsigned short h = f2bf(wf[j]);
        whi[kt][j] = (short)h;
        wlo[kt][j] = (short)f2bf(wf[j] - bf2f(h));
      }
    }
    #pragma unroll
    for (int tt = 0; tt < 4; tt++) {
      const int t = tt * 16 + l16;
      f32x4 acc = {0.f, 0.f, 0.f, 0.f};
      #pragma unroll
      for (int kt = 0; kt < 2; kt++) {
        bf16x8 ob = *(const bf16x8*)
            &lds[8192 + t * 64 + ((((kt << 2) + l4) ^ (t & 7)) << 3)];
        acc = MFMA(wlo[kt], ob, acc);
        acc = MFMA(whi[kt], ob, acc);
      }
      if (t < PP) {
        const int ph = t / 7, pw = t - ph * 7;
        const size_t col = (size_t)(pi * 7 + ph) * NS + (pj * 7 + pw);
        #pragma unroll
        for (int i = 0; i < 4; i++) {
          const int oc = wid * 16 + l4 * 4 + i;
          P[((size_t)b * 64 + oc) * (NS * NS) + col] = acc[i];
        }
      }
    }
  }
}

// ---------------------------------------------------------------------------
// Kernel 2: merge. out[b][oc][h][w] = bp[oc] + (sampled ? P : 0). float4.
// ---------------------------------------------------------------------------
__global__ __launch_bounds__(256) void k2_merge(
    const float* __restrict__ P, const float* __restrict__ bp,
    float* __restrict__ out)
{
  __shared__ float bps[64];
  __shared__ int wsmap[256];
  const int tid = threadIdx.x;
  const int b = blockIdx.x / HH, h = blockIdx.x % HH;
  if (tid < 64) bps[tid] = bp[tid];
  {
    int w = tid, wsv = -1;
    for (int pj = 0; pj < NPW; pj++) {
      int r = w - pj * STRIDE;
      if (r >= 0 && r <= (PDIM - 1) * DIL && (r % DIL) == 0) { wsv = pj * PDIM + r / DIL; break; }
    }
    wsmap[tid] = wsv;
  }
  int hs = -1;
  for (int pi = 0; pi < NPW; pi++) {
    int r = h - pi * STRIDE;
    if (r >= 0 && r <= (PDIM - 1) * DIL && (r % DIL) == 0) { hs = pi * PDIM + r / DIL; break; }
  }
  __syncthreads();

  const int wq = tid & 63;   // float4 column
  const int ocq = tid >> 6;  // 0..3
  float4* out4 = (float4*)out;

  if (hs < 0) {
    #pragma unroll 4
    for (int oc = ocq; oc < 64; oc += 4) {
      float bv = bps[oc];
      out4[(((size_t)b * 64 + oc) * HH + h) * 64 + wq] = make_float4(bv, bv, bv, bv);
    }
    return;
  }
  const int ws0 = wsmap[wq * 4 + 0], ws1 = wsmap[wq * 4 + 1];
  const int ws2 = wsmap[wq * 4 + 2], ws3 = wsmap[wq * 4 + 3];
  #pragma unroll 4
  for (int oc = ocq; oc < 64; oc += 4) {
    float bv = bps[oc];
    size_t rbase = (((size_t)b * 64 + oc) * NS + hs) * NS;
    float4 v = make_float4(bv, bv, bv, bv);
    if (ws0 >= 0) v.x += P[rbase + ws0];
    if (ws1 >= 0) v.y += P[rbase + ws1];
    if (ws2 >= 0) v.z += P[rbase + ws2];
    if (ws3 >= 0) v.w += P[rbase + ws3];
    out4[(((size_t)b * 64 + oc) * HH + h) * 64 + wq] = v;
  }
}

extern "C" void kernel_launch(void* const* d_in, const int* in_sizes, int n_in,
                              void* d_out, int out_size, void* d_ws, size_t ws_size,
                              hipStream_t stream) {
  const float* x1 = (const float*)d_in[0];
  const float* x2 = (const float*)d_in[1];
  const float* Wk = (const float*)d_in[2];
  const float* bk = (const float*)d_in[3];
  const float* Wv = (const float*)d_in[4];
  const float* bv = (const float*)d_in[5];
  const float* Wp = (const float*)d_in[6];
  const float* bp = (const float*)d_in[7];
  float* P = (float*)d_ws;  // 8*64*84*84 floats = 14.45 MB
  float* out = (float*)d_out;

  k1_fused<<<dim3(BB * SPP), dim3(256), 0, stream>>>(x1, x2, Wk, bk, Wv, bv, Wp, P);
  k2_merge<<<dim3(BB * HH), dim3(256), 0, stream>>>(P, bp, out);
}